// Round 5
// baseline (111.288 us; speedup 1.0000x reference)
//
#include <hip/hip_runtime.h>
#include <math.h>

// CapsuleLayer dynamic routing, fully fused: one block per batch element.
// B=256, O=10, U=36, S=32, E=16, F=8, N=1152, 3 routing iterations.
//
// u_hat is never materialized:
//   v_pre[o,e]  = sum_{u,f} W[o,u,e,f] * cx[o,u,f],  cx[o,u,f] = sum_s c[o,n]*x[n,f]
//   b[o,n]     += sum_f x[n,f] * wv[o,u,f],          wv[o,u,f] = sum_e W[o,u,e,f]*v[o,e]
//
// Round-4: same phase structure as round 3 (wide phases, it0-cx folded into a
// prologue shuffle-reduced sx, squash folded into wv) but scratch-free:
//  - wv-phase v rebuild uses four named float4s (macros, no indexable array)
//  - prologue butterfly reduces float4 components (no r[8] array)
//  - __launch_bounds__(576,2): 256-VGPR budget, no allocator squeeze
//  - v_pre: uniform it==0 branch hoisted out of the loop; both paths fully
//    unrolled so all 24 W float4 loads issue before the dot chain (MLP)
//
// LDS swizzles: u-stride is 32 rows -> 32*pitch = 0 mod 32 banks for any pitch:
//   x row n, 16B half h  -> word u*256 + (((s<<1)+h+u)&63)*4
//   c[o][n]              -> word o*1152 + u*32 + ((s+u)&31)

namespace {

constexpr int kO = 10;
constexpr int kU = 36;
constexpr int kS = 32;
constexpr int kE = 16;
constexpr int kF = 8;
constexpr int kN = kU * kS;    // 1152
constexpr int kIters = 3;
constexpr int kThreads = 576;  // 9 waves
constexpr int kRows = 2;
constexpr int kPitch = 12;     // padded (o,u)-row pitch for s_cx/s_wv

__launch_bounds__(kThreads, 2)
__global__ void caps_routing_kernel(const float* __restrict__ xg,
                                    const float* __restrict__ Wg,
                                    float* __restrict__ outg) {
    __shared__ float s_x[kN * kF];             // 36.9 KB, swizzled
    __shared__ float s_c[kO * kN];             // 46.1 KB, swizzled
    __shared__ float s_cx[kO * kU * kPitch];   // 17.3 KB
    __shared__ float s_wv[kO * kU * kPitch];   // 17.3 KB
    __shared__ float s_vp[kO * kE * 3];        //  1.9 KB (3 u-chunk partials)
    __shared__ float s_sx[kU * kF];            //  1.2 KB (sum_s x, for it=0)
    // total ~121 KB

    const int t = threadIdx.x;
    const int b = blockIdx.x;

    float xr[kRows][kF];   // this thread's x rows (static indexing only)
    float br[kRows][kO];   // routing logits for owned rows
    int   ru[kRows], rrot[kRows];

    // ---- prologue: load x rows -> regs + swizzled LDS; half-wave reduce sx ----
#pragma unroll
    for (int k = 0; k < kRows; ++k) {
        const int n = t + k * kThreads;
        const int u = n >> 5;
        const int s = n & 31;
        ru[k]   = u;
        rrot[k] = (s + u) & 31;
        const float4* src =
            reinterpret_cast<const float4*>(xg + ((size_t)b * kN + n) * kF);
        const float4 a0 = src[0];
        const float4 a1 = src[1];
        xr[k][0] = a0.x; xr[k][1] = a0.y; xr[k][2] = a0.z; xr[k][3] = a0.w;
        xr[k][4] = a1.x; xr[k][5] = a1.y; xr[k][6] = a1.z; xr[k][7] = a1.w;
        const int sl0 = ((s << 1) + 0 + u) & 63;
        const int sl1 = ((s << 1) + 1 + u) & 63;
        *reinterpret_cast<float4*>(&s_x[u * 256 + sl0 * 4]) = a0;
        *reinterpret_cast<float4*>(&s_x[u * 256 + sl1 * 4]) = a1;

        // sx[u][f] = sum_s x[u,s,f]: the 32 rows of u are exactly one half-wave.
        // Butterfly on float4 components (named members -> guaranteed registers).
        float4 r0 = a0, r1 = a1;
#pragma unroll
        for (int m = 1; m <= 16; m <<= 1) {
            r0.x += __shfl_xor(r0.x, m); r0.y += __shfl_xor(r0.y, m);
            r0.z += __shfl_xor(r0.z, m); r0.w += __shfl_xor(r0.w, m);
            r1.x += __shfl_xor(r1.x, m); r1.y += __shfl_xor(r1.y, m);
            r1.z += __shfl_xor(r1.z, m); r1.w += __shfl_xor(r1.w, m);
        }
        if (s == 0) {
            *reinterpret_cast<float4*>(&s_sx[u * kF + 0]) = r0;
            *reinterpret_cast<float4*>(&s_sx[u * kF + 4]) = r1;
        }
#pragma unroll
        for (int o = 0; o < kO; ++o) br[k][o] = 0.f;
    }
    __syncthreads();

    for (int it = 0; it <= kIters; ++it) {
        // ---- cx[o][u][f] = sum_s c[o][n]*x[n][f]; thread=(o,u), 360 active ----
        // (skipped at it=0: c is uniform 0.1, folded into v_pre via s_sx)
        if (it > 0) {
            if (t < kO * kU) {
                const int o = t / kU;
                const int u = t - o * kU;
                float a0[kF] = {0, 0, 0, 0, 0, 0, 0, 0};
#pragma unroll 8
                for (int s = 0; s < kS; ++s) {
                    const int rot = (s + u) & 31;
                    const int sl0 = ((s << 1) + 0 + u) & 63;
                    const int sl1 = ((s << 1) + 1 + u) & 63;
                    const float4 xa =
                        *reinterpret_cast<const float4*>(&s_x[u * 256 + sl0 * 4]);
                    const float4 xb =
                        *reinterpret_cast<const float4*>(&s_x[u * 256 + sl1 * 4]);
                    const float c0 = s_c[o * kN + u * 32 + rot];
                    a0[0] += c0 * xa.x; a0[1] += c0 * xa.y;
                    a0[2] += c0 * xa.z; a0[3] += c0 * xa.w;
                    a0[4] += c0 * xb.x; a0[5] += c0 * xb.y;
                    a0[6] += c0 * xb.z; a0[7] += c0 * xb.w;
                }
                float4* d = reinterpret_cast<float4*>(&s_cx[(o * kU + u) * kPitch]);
                d[0] = make_float4(a0[0], a0[1], a0[2], a0[3]);
                d[1] = make_float4(a0[4], a0[5], a0[6], a0[7]);
            }
            __syncthreads();
        }

        // ---- v_pre partials: thread=(o,e,uc), 480 active; 12 u's each ----
        if (t < kO * kE * 3) {
            const int o  = t / (kE * 3);
            const int r  = t - o * (kE * 3);
            const int e  = r / 3;
            const int uc = r - e * 3;
            const int u0 = uc * 12;
            float acc = 0.f;
            if (it == 0) {
                const float* wrow = Wg + ((size_t)(o * kU + u0) * kE + e) * kF;
#pragma unroll
                for (int ui = 0; ui < 12; ++ui) {
                    const float4* wp = reinterpret_cast<const float4*>(wrow);
                    const float4 w0 = wp[0];
                    const float4 w1 = wp[1];
                    const float4* cp =
                        reinterpret_cast<const float4*>(&s_sx[(u0 + ui) * kF]);
                    const float4 c0 = cp[0];
                    const float4 c1 = cp[1];
                    acc += w0.x * c0.x + w0.y * c0.y + w0.z * c0.z + w0.w * c0.w;
                    acc += w1.x * c1.x + w1.y * c1.y + w1.z * c1.z + w1.w * c1.w;
                    wrow += kE * kF;
                }
                acc *= 0.1f;
            } else {
                const float* wrow = Wg + ((size_t)(o * kU + u0) * kE + e) * kF;
#pragma unroll
                for (int ui = 0; ui < 12; ++ui) {
                    const float4* wp = reinterpret_cast<const float4*>(wrow);
                    const float4 w0 = wp[0];
                    const float4 w1 = wp[1];
                    const float4* cp = reinterpret_cast<const float4*>(
                        &s_cx[(o * kU + u0 + ui) * kPitch]);
                    const float4 c0 = cp[0];
                    const float4 c1 = cp[1];
                    acc += w0.x * c0.x + w0.y * c0.y + w0.z * c0.z + w0.w * c0.w;
                    acc += w1.x * c1.x + w1.y * c1.y + w1.z * c1.z + w1.w * c1.w;
                    wrow += kE * kF;
                }
            }
            s_vp[(o * kE + e) * 3 + uc] = acc;
        }
        __syncthreads();

        // ---- final pass: squash + store output, done ----
        if (it == kIters) {
            if (t < kO * kE) {
                const float vsum = s_vp[t * 3 + 0] + s_vp[t * 3 + 1] + s_vp[t * 3 + 2];
                float n2 = vsum * vsum;
#pragma unroll
                for (int m = 1; m <= 8; m <<= 1) n2 += __shfl_xor(n2, m);
                const float scale = sqrtf(n2) / (1.f + n2);
                outg[(size_t)b * kO * kE + t] = vsum * scale;
            }
            break;
        }

        // ---- wv[o][u][f] = sum_e W[o][u][e][f]*v[o][e]; thread=(o,u), 360 active
        // squash folded in; v rebuilt into named float4s (no indexable array)
        if (t < kO * kU) {
            const int o = t / kU;
            const int u = t - o * kU;
#define SUMVP(E_) (s_vp[(o * kE + (E_)) * 3 + 0] + \
                   s_vp[(o * kE + (E_)) * 3 + 1] + \
                   s_vp[(o * kE + (E_)) * 3 + 2])
            float4 va, vb, vc, vd;
            va.x = SUMVP(0);  va.y = SUMVP(1);  va.z = SUMVP(2);  va.w = SUMVP(3);
            vb.x = SUMVP(4);  vb.y = SUMVP(5);  vb.z = SUMVP(6);  vb.w = SUMVP(7);
            vc.x = SUMVP(8);  vc.y = SUMVP(9);  vc.z = SUMVP(10); vc.w = SUMVP(11);
            vd.x = SUMVP(12); vd.y = SUMVP(13); vd.z = SUMVP(14); vd.w = SUMVP(15);
#undef SUMVP
            const float n2 =
                va.x * va.x + va.y * va.y + va.z * va.z + va.w * va.w +
                vb.x * vb.x + vb.y * vb.y + vb.z * vb.z + vb.w * vb.w +
                vc.x * vc.x + vc.y * vc.y + vc.z * vc.z + vc.w * vc.w +
                vd.x * vd.x + vd.y * vd.y + vd.z * vd.z + vd.w * vd.w;
            const float scale = sqrtf(n2) / (1.f + n2);
            const float* wbase = Wg + (size_t)(o * kU + u) * kE * kF;
            float4 acc0 = make_float4(0.f, 0.f, 0.f, 0.f);
            float4 acc1 = make_float4(0.f, 0.f, 0.f, 0.f);
#define WSTEP(VE_, E_)                                                        \
    {                                                                         \
        const float4* wp =                                                    \
            reinterpret_cast<const float4*>(wbase + (E_) * kF);               \
        const float4 w0 = wp[0];                                              \
        const float4 w1 = wp[1];                                              \
        const float ve = (VE_) * scale;                                       \
        acc0.x += ve * w0.x; acc0.y += ve * w0.y;                             \
        acc0.z += ve * w0.z; acc0.w += ve * w0.w;                             \
        acc1.x += ve * w1.x; acc1.y += ve * w1.y;                             \
        acc1.z += ve * w1.z; acc1.w += ve * w1.w;                             \
    }
            WSTEP(va.x, 0)  WSTEP(va.y, 1)  WSTEP(va.z, 2)  WSTEP(va.w, 3)
            WSTEP(vb.x, 4)  WSTEP(vb.y, 5)  WSTEP(vb.z, 6)  WSTEP(vb.w, 7)
            WSTEP(vc.x, 8)  WSTEP(vc.y, 9)  WSTEP(vc.z, 10) WSTEP(vc.w, 11)
            WSTEP(vd.x, 12) WSTEP(vd.y, 13) WSTEP(vd.z, 14) WSTEP(vd.w, 15)
#undef WSTEP
            float4* d = reinterpret_cast<float4*>(&s_wv[(o * kU + u) * kPitch]);
            d[0] = acc0;
            d[1] = acc1;
        }
        __syncthreads();

        // ---- b[o,n] += x[n,:].wv[o,u,:]; thread-local softmax over o; write c ----
#pragma unroll
        for (int k = 0; k < kRows; ++k) {
            const int u   = ru[k];
            const int rot = rrot[k];
            float mx = -3.4e38f;
#pragma unroll
            for (int o = 0; o < kO; ++o) {
                const float4* wp =
                    reinterpret_cast<const float4*>(&s_wv[(o * kU + u) * kPitch]);
                const float4 w0 = wp[0];  // broadcast across the half-wave (same u)
                const float4 w1 = wp[1];
                br[k][o] += w0.x * xr[k][0] + w0.y * xr[k][1] + w0.z * xr[k][2] + w0.w * xr[k][3]
                          + w1.x * xr[k][4] + w1.y * xr[k][5] + w1.z * xr[k][6] + w1.w * xr[k][7];
                mx = fmaxf(mx, br[k][o]);
            }
            float ex[kO];
            float sum = 0.f;
#pragma unroll
            for (int o = 0; o < kO; ++o) {
                ex[o] = __expf(br[k][o] - mx);
                sum += ex[o];
            }
            const float inv = 1.f / sum;
#pragma unroll
            for (int o = 0; o < kO; ++o) s_c[o * kN + u * 32 + rot] = ex[o] * inv;
        }
        __syncthreads();
    }
}

}  // namespace

extern "C" void kernel_launch(void* const* d_in, const int* in_sizes, int n_in,
                              void* d_out, int out_size, void* d_ws, size_t ws_size,
                              hipStream_t stream) {
    const float* x = (const float*)d_in[0];  // (B, 1152, 8) fp32
    const float* W = (const float*)d_in[1];  // (10, 36, 16, 8) fp32
    float* out = (float*)d_out;              // (B, 10, 16) fp32

    const int batch = in_sizes[0] / (kN * kF);  // 256
    caps_routing_kernel<<<dim3(batch), dim3(kThreads), 0, stream>>>(x, W, out);
}

// Round 7
// 105.372 us; speedup vs baseline: 1.0561x; 1.0561x over previous
//
#include <hip/hip_runtime.h>
#include <math.h>

// CapsuleLayer dynamic routing, fully fused: one block per batch element.
// B=256, O=10, U=36, S=32, E=16, F=8, N=1152, 3 routing iterations.
//
// u_hat is never materialized:
//   v_pre[o,e]  = sum_{u,f} W[o,u,e,f] * cx[o,u,f],  cx[o,u,f] = sum_s c[o,n]*x[n,f]
//   b[o,n]     += sum_f x[n,f] * wv[o,u,f],          wv[o,u,f] = sum_e W[o,u,e,f]*v[o,e]
//
// Round-7 = round-6 structure with the x-swizzle bug fixed. Round 6's
// ((s&16)>>2) offset term was NON-BIJECTIVE (s=30 collided with s=0, s=31
// with s=1 -> LDS rows overwritten -> absmax 0.13). Reverted to the proven
// round-5 swizzle; the 2-way bank alias it allows between s-halves is free
// on gfx950 (m136: 2 lanes/bank = 1.02x).
//
// Structure: 512 threads = 8 waves = exactly 2/SIMD (576/9 gave {3,2,2,2}
// skew; every phase ran at the 3-wave SIMD's pace). Phase maps are per-wave-
// uniform (l < K within each wave) so all SIMDs carry equal load. cx split
// over s-halves: thread (o-pair, u, h) does 16 s-steps (serial depth halved,
// x-reads amortized over 2 o's), halves combined via adjacent-lane
// __shfl_xor(1). Rows: 2/thread + third row on 128 SIMD-balanced threads.
//
// LDS swizzles: u-stride is 32 rows -> 32*pitch = 0 mod 32 banks for any pitch:
//   x row (u,s), 16B half h' -> word u*256 + ((2s + h' + u)&63)*4
//   c[o][n]                  -> word o*1152 + u*32 + ((s+u)&31)

namespace {

constexpr int kO = 10;
constexpr int kU = 36;
constexpr int kS = 32;
constexpr int kE = 16;
constexpr int kF = 8;
constexpr int kN = kU * kS;    // 1152
constexpr int kIters = 3;
constexpr int kThreads = 512;  // 8 waves, 2 per SIMD
constexpr int kPitch = 12;     // padded (o,u)-row pitch for s_cx/s_wv

__launch_bounds__(kThreads, 2)
__global__ void caps_routing_kernel(const float* __restrict__ xg,
                                    const float* __restrict__ Wg,
                                    float* __restrict__ outg) {
  __shared__ float s_x[kN * kF];            // 36.9 KB, swizzled
  __shared__ float s_c[kO * kN];            // 46.1 KB, swizzled
  __shared__ float s_cx[kO * kU * kPitch];  // 17.3 KB
  __shared__ float s_wv[kO * kU * kPitch];  // 17.3 KB
  __shared__ float s_vp[kO * kE * 3];       //  1.9 KB
  __shared__ float s_sx[kU * kF];           //  1.2 KB (sum_s x, for it=0)
  // total ~121 KB

  const int t = threadIdx.x;
  const int w = t >> 6;
  const int l = t & 63;
  const int b = blockIdx.x;

  float xr0[kF], xr1[kF], xr2[kF];
  float br0[kO], br1[kO], br2[kO];
  const bool has3 = (w < 4) && (l < 32);  // third row: 128 threads, SIMD-balanced

  const int u0r = t >> 5;          // rows 0..511    -> u 0..15
  const int s0r = t & 31;
  const int rot0 = (s0r + u0r) & 31;
  const int u1r = 16 + (t >> 5);   // rows 512..1023 -> u 16..31
  const int rot1 = (s0r + u1r) & 31;
  const int u2r = 32 + w;          // rows 1024..1151 -> u 32..35
  const int rot2 = (l + u2r) & 31;

  // ---- prologue: load rows -> regs + swizzled LDS; half-wave butterfly sx ----
#define STAGEROW(XR, N, U, S)                                                 \
  {                                                                           \
    const float4* src_ =                                                      \
        reinterpret_cast<const float4*>(xg + ((size_t)b * kN + (N)) * kF);    \
    const float4 a0_ = src_[0];                                               \
    const float4 a1_ = src_[1];                                               \
    XR[0] = a0_.x; XR[1] = a0_.y; XR[2] = a0_.z; XR[3] = a0_.w;               \
    XR[4] = a1_.x; XR[5] = a1_.y; XR[6] = a1_.z; XR[7] = a1_.w;               \
    const int sl0_ = (((S) << 1) + (U)) & 63;                                 \
    const int sl1_ = (((S) << 1) + 1 + (U)) & 63;                             \
    *reinterpret_cast<float4*>(&s_x[(U) * 256 + sl0_ * 4]) = a0_;             \
    *reinterpret_cast<float4*>(&s_x[(U) * 256 + sl1_ * 4]) = a1_;             \
    float4 r0_ = a0_, r1_ = a1_;                                              \
    _Pragma("unroll")                                                         \
    for (int m_ = 1; m_ <= 16; m_ <<= 1) {                                    \
      r0_.x += __shfl_xor(r0_.x, m_); r0_.y += __shfl_xor(r0_.y, m_);         \
      r0_.z += __shfl_xor(r0_.z, m_); r0_.w += __shfl_xor(r0_.w, m_);         \
      r1_.x += __shfl_xor(r1_.x, m_); r1_.y += __shfl_xor(r1_.y, m_);         \
      r1_.z += __shfl_xor(r1_.z, m_); r1_.w += __shfl_xor(r1_.w, m_);         \
    }                                                                         \
    if ((S) == 0) {                                                           \
      *reinterpret_cast<float4*>(&s_sx[(U) * kF + 0]) = r0_;                  \
      *reinterpret_cast<float4*>(&s_sx[(U) * kF + 4]) = r1_;                  \
    }                                                                         \
  }

  STAGEROW(xr0, t, u0r, s0r)
  STAGEROW(xr1, t + 512, u1r, s0r)
  if (has3) STAGEROW(xr2, 1024 + w * 32 + l, u2r, l)
#undef STAGEROW
#pragma unroll
  for (int o = 0; o < kO; ++o) { br0[o] = 0.f; br1[o] = 0.f; br2[o] = 0.f; }
  __syncthreads();

  for (int it = 0; it <= kIters; ++it) {
    // ---- cx[o][u][f] = sum_s c[o][n]*x[n][f] ----
    // thread (op,u,h): o-pair op, s-half h; 360 active spread as l<46 per wave.
    // Pairing: i = w*46+l, 46 even -> lane parity == i parity, so (h0,h1) of
    // each (op,u) are adjacent lanes; combined via __shfl_xor(1).
    if (it > 0) {
      if (l < 46) {
        const int i = w * 46 + l;
        if (i < 360) {
          const int op  = i / 72;
          const int rem = i - op * 72;
          const int u   = rem >> 1;
          const int h   = rem & 1;
          const int o0  = op * 2, o1 = o0 + 1;
          float4 p00 = make_float4(0.f, 0.f, 0.f, 0.f);
          float4 p01 = make_float4(0.f, 0.f, 0.f, 0.f);
          float4 p10 = make_float4(0.f, 0.f, 0.f, 0.f);
          float4 p11 = make_float4(0.f, 0.f, 0.f, 0.f);
#pragma unroll 4
          for (int j = 0; j < 16; ++j) {
            const int s   = h * 16 + j;
            const int rot = (s + u) & 31;
            const int sl0 = ((s << 1) + u) & 63;
            const int sl1 = ((s << 1) + 1 + u) & 63;
            const float4 xa =
                *reinterpret_cast<const float4*>(&s_x[u * 256 + sl0 * 4]);
            const float4 xb =
                *reinterpret_cast<const float4*>(&s_x[u * 256 + sl1 * 4]);
            const float c0 = s_c[o0 * kN + u * 32 + rot];
            const float c1 = s_c[o1 * kN + u * 32 + rot];
            p00.x += c0 * xa.x; p00.y += c0 * xa.y; p00.z += c0 * xa.z; p00.w += c0 * xa.w;
            p01.x += c0 * xb.x; p01.y += c0 * xb.y; p01.z += c0 * xb.z; p01.w += c0 * xb.w;
            p10.x += c1 * xa.x; p10.y += c1 * xa.y; p10.z += c1 * xa.z; p10.w += c1 * xa.w;
            p11.x += c1 * xb.x; p11.y += c1 * xb.y; p11.z += c1 * xb.z; p11.w += c1 * xb.w;
          }
          // combine the two s-halves (adjacent lanes, same (op,u))
          p00.x += __shfl_xor(p00.x, 1); p00.y += __shfl_xor(p00.y, 1);
          p00.z += __shfl_xor(p00.z, 1); p00.w += __shfl_xor(p00.w, 1);
          p01.x += __shfl_xor(p01.x, 1); p01.y += __shfl_xor(p01.y, 1);
          p01.z += __shfl_xor(p01.z, 1); p01.w += __shfl_xor(p01.w, 1);
          p10.x += __shfl_xor(p10.x, 1); p10.y += __shfl_xor(p10.y, 1);
          p10.z += __shfl_xor(p10.z, 1); p10.w += __shfl_xor(p10.w, 1);
          p11.x += __shfl_xor(p11.x, 1); p11.y += __shfl_xor(p11.y, 1);
          p11.z += __shfl_xor(p11.z, 1); p11.w += __shfl_xor(p11.w, 1);
          if (h == 0) {
            float4* d = reinterpret_cast<float4*>(&s_cx[(o0 * kU + u) * kPitch]);
            d[0] = p00; d[1] = p01;
          } else {
            float4* d = reinterpret_cast<float4*>(&s_cx[(o1 * kU + u) * kPitch]);
            d[0] = p10; d[1] = p11;
          }
        }
      }
      __syncthreads();
    }

    // ---- v_pre partials: thread=(o,e,uc), 480 active as l<60 per wave ----
    if (l < 60) {
      const int i  = w * 60 + l;  // 0..479
      const int o  = i / 48;
      const int r  = i - o * 48;
      const int e  = r / 3;
      const int uc = r - e * 3;
      const int u0 = uc * 12;
      float accA = 0.f, accB = 0.f;
      const float* wrow = Wg + ((size_t)(o * kU + u0) * kE + e) * kF;
      if (it == 0) {
#pragma unroll 4
        for (int ui = 0; ui < 12; ++ui) {
          const float4* wp = reinterpret_cast<const float4*>(wrow);
          const float4 w0 = wp[0];
          const float4 w1 = wp[1];
          const float4* cp =
              reinterpret_cast<const float4*>(&s_sx[(u0 + ui) * kF]);
          const float4 c0 = cp[0];
          const float4 c1 = cp[1];
          accA += w0.x * c0.x + w0.y * c0.y + w0.z * c0.z + w0.w * c0.w;
          accB += w1.x * c1.x + w1.y * c1.y + w1.z * c1.z + w1.w * c1.w;
          wrow += kE * kF;
        }
        accA = (accA + accB) * 0.1f;
      } else {
#pragma unroll 4
        for (int ui = 0; ui < 12; ++ui) {
          const float4* wp = reinterpret_cast<const float4*>(wrow);
          const float4 w0 = wp[0];
          const float4 w1 = wp[1];
          const float4* cp = reinterpret_cast<const float4*>(
              &s_cx[(o * kU + u0 + ui) * kPitch]);
          const float4 c0 = cp[0];
          const float4 c1 = cp[1];
          accA += w0.x * c0.x + w0.y * c0.y + w0.z * c0.z + w0.w * c0.w;
          accB += w1.x * c1.x + w1.y * c1.y + w1.z * c1.z + w1.w * c1.w;
          wrow += kE * kF;
        }
        accA += accB;
      }
      s_vp[(o * kE + e) * 3 + uc] = accA;
    }
    __syncthreads();

    // ---- final pass: squash + store output, done ----
    if (it == kIters) {
      if (t < kO * kE) {
        const float vsum = s_vp[t * 3 + 0] + s_vp[t * 3 + 1] + s_vp[t * 3 + 2];
        float n2 = vsum * vsum;
#pragma unroll
        for (int m = 1; m <= 8; m <<= 1) n2 += __shfl_xor(n2, m);
        const float scale = sqrtf(n2) / (1.f + n2);
        outg[(size_t)b * kO * kE + t] = vsum * scale;
      }
      break;
    }

    // ---- wv[o][u][f] = sum_e W[o][u][e][f]*v[o][e]; 360 active as l<45 ----
    // squash folded in; v rebuilt into named float4s (broadcast s_vp reads)
    if (l < 45) {
      const int i = w * 45 + l;  // 0..359
      const int o = i / 36;
      const int u = i - o * 36;
#define SUMVP(E_) (s_vp[(o * kE + (E_)) * 3 + 0] + \
                   s_vp[(o * kE + (E_)) * 3 + 1] + \
                   s_vp[(o * kE + (E_)) * 3 + 2])
      float4 va, vb, vc, vd;
      va.x = SUMVP(0);  va.y = SUMVP(1);  va.z = SUMVP(2);  va.w = SUMVP(3);
      vb.x = SUMVP(4);  vb.y = SUMVP(5);  vb.z = SUMVP(6);  vb.w = SUMVP(7);
      vc.x = SUMVP(8);  vc.y = SUMVP(9);  vc.z = SUMVP(10); vc.w = SUMVP(11);
      vd.x = SUMVP(12); vd.y = SUMVP(13); vd.z = SUMVP(14); vd.w = SUMVP(15);
#undef SUMVP
      const float n2 =
          va.x * va.x + va.y * va.y + va.z * va.z + va.w * va.w +
          vb.x * vb.x + vb.y * vb.y + vb.z * vb.z + vb.w * vb.w +
          vc.x * vc.x + vc.y * vc.y + vc.z * vc.z + vc.w * vc.w +
          vd.x * vd.x + vd.y * vd.y + vd.z * vd.z + vd.w * vd.w;
      const float scale = sqrtf(n2) / (1.f + n2);
      const float* wbase = Wg + (size_t)(o * kU + u) * kE * kF;
      float4 acc0 = make_float4(0.f, 0.f, 0.f, 0.f);
      float4 acc1 = make_float4(0.f, 0.f, 0.f, 0.f);
#define WSTEP(VE_, E_)                                                        \
  {                                                                           \
    const float4* wp = reinterpret_cast<const float4*>(wbase + (E_) * kF);    \
    const float4 w0 = wp[0];                                                  \
    const float4 w1 = wp[1];                                                  \
    const float ve = (VE_) * scale;                                           \
    acc0.x += ve * w0.x; acc0.y += ve * w0.y;                                 \
    acc0.z += ve * w0.z; acc0.w += ve * w0.w;                                 \
    acc1.x += ve * w1.x; acc1.y += ve * w1.y;                                 \
    acc1.z += ve * w1.z; acc1.w += ve * w1.w;                                 \
  }
      WSTEP(va.x, 0)  WSTEP(va.y, 1)  WSTEP(va.z, 2)  WSTEP(va.w, 3)
      WSTEP(vb.x, 4)  WSTEP(vb.y, 5)  WSTEP(vb.z, 6)  WSTEP(vb.w, 7)
      WSTEP(vc.x, 8)  WSTEP(vc.y, 9)  WSTEP(vc.z, 10) WSTEP(vc.w, 11)
      WSTEP(vd.x, 12) WSTEP(vd.y, 13) WSTEP(vd.z, 14) WSTEP(vd.w, 15)
#undef WSTEP
      float4* d = reinterpret_cast<float4*>(&s_wv[(o * kU + u) * kPitch]);
      d[0] = acc0;
      d[1] = acc1;
    }
    __syncthreads();

    // ---- b[o,n] += x[n,:].wv[o,u,:]; thread-local softmax over o; write c ----
#define BSMROW(XR, BR, U, ROT)                                                \
  {                                                                           \
    float mx_ = -3.4e38f;                                                     \
    _Pragma("unroll")                                                         \
    for (int o_ = 0; o_ < kO; ++o_) {                                         \
      const float4* wp_ =                                                     \
          reinterpret_cast<const float4*>(&s_wv[(o_ * kU + (U)) * kPitch]);   \
      const float4 w0_ = wp_[0];                                              \
      const float4 w1_ = wp_[1];                                              \
      BR[o_] += w0_.x * XR[0] + w0_.y * XR[1] + w0_.z * XR[2] + w0_.w * XR[3] \
              + w1_.x * XR[4] + w1_.y * XR[5] + w1_.z * XR[6] + w1_.w * XR[7];\
      mx_ = fmaxf(mx_, BR[o_]);                                               \
    }                                                                         \
    float ex_[kO];                                                            \
    float sum_ = 0.f;                                                         \
    _Pragma("unroll")                                                         \
    for (int o_ = 0; o_ < kO; ++o_) {                                         \
      ex_[o_] = __expf(BR[o_] - mx_);                                         \
      sum_ += ex_[o_];                                                        \
    }                                                                         \
    const float inv_ = 1.f / sum_;                                            \
    _Pragma("unroll")                                                         \
    for (int o_ = 0; o_ < kO; ++o_)                                           \
      s_c[o_ * kN + (U) * 32 + (ROT)] = ex_[o_] * inv_;                       \
  }
    BSMROW(xr0, br0, u0r, rot0)
    BSMROW(xr1, br1, u1r, rot1)
    if (has3) BSMROW(xr2, br2, u2r, rot2)
#undef BSMROW
    __syncthreads();
  }
}

}  // namespace

extern "C" void kernel_launch(void* const* d_in, const int* in_sizes, int n_in,
                              void* d_out, int out_size, void* d_ws, size_t ws_size,
                              hipStream_t stream) {
  const float* x = (const float*)d_in[0];  // (B, 1152, 8) fp32
  const float* W = (const float*)d_in[1];  // (10, 36, 16, 8) fp32
  float* out = (float*)d_out;              // (B, 10, 16) fp32

  const int batch = in_sizes[0] / (kN * kF);  // 256
  caps_routing_kernel<<<dim3(batch), dim3(kThreads), 0, stream>>>(x, W, out);
}

// Round 8
// 104.842 us; speedup vs baseline: 1.0615x; 1.0051x over previous
//
#include <hip/hip_runtime.h>
#include <math.h>

// CapsuleLayer dynamic routing, fully fused: one block per batch element.
// B=256, O=10, U=36, S=32, E=16, F=8, N=1152, 3 routing iterations.
//
// u_hat is never materialized:
//   v_pre[o,e]  = sum_{u,f} W[o,u,e,f] * cx[o,u,f],  cx[o,u,f] = sum_s c[o,n]*x[n,f]
//   b[o,n]     += sum_f x[n,f] * wv[o,u,f],          wv[o,u,f] = sum_e W[o,u,e,f]*v[o,e]
//
// Round-8 = round-7 + v_pre W hoisted to registers (single change).
// v_pre's W rows are ITERATION-INVARIANT per thread (o,e,uc): 24 float4s.
// Loading them once in the prologue removes 4 of 7 W-streaming phases
// (4 x 184 KB/block L2 traffic + latency) from the serial chain; v_pre
// becomes pure LDS+FMA. VGPR 108 -> ~220 (256 budget at 8 waves, 2/SIMD).
//
// Structure (round 7): 512 threads = 8 waves = 2/SIMD, per-wave-uniform phase
// maps, cx split over s-halves (shfl_xor(1) combine), 2 rows/thread + third
// row on 128 SIMD-balanced threads.
//
// LDS swizzles: u-stride is 32 rows -> 32*pitch = 0 mod 32 banks for any pitch:
//   x row (u,s), 16B half h' -> word u*256 + ((2s + h' + u)&63)*4
//   c[o][n]                  -> word o*1152 + u*32 + ((s+u)&31)

namespace {

constexpr int kO = 10;
constexpr int kU = 36;
constexpr int kS = 32;
constexpr int kE = 16;
constexpr int kF = 8;
constexpr int kN = kU * kS;    // 1152
constexpr int kIters = 3;
constexpr int kThreads = 512;  // 8 waves, 2 per SIMD
constexpr int kPitch = 12;     // padded (o,u)-row pitch for s_cx/s_wv

__launch_bounds__(kThreads, 2)
__global__ void caps_routing_kernel(const float* __restrict__ xg,
                                    const float* __restrict__ Wg,
                                    float* __restrict__ outg) {
  __shared__ float s_x[kN * kF];            // 36.9 KB, swizzled
  __shared__ float s_c[kO * kN];            // 46.1 KB, swizzled
  __shared__ float s_cx[kO * kU * kPitch];  // 17.3 KB
  __shared__ float s_wv[kO * kU * kPitch];  // 17.3 KB
  __shared__ float s_vp[kO * kE * 3];       //  1.9 KB
  __shared__ float s_sx[kU * kF];           //  1.2 KB (sum_s x, for it=0)
  // total ~121 KB

  const int t = threadIdx.x;
  const int w = t >> 6;
  const int l = t & 63;
  const int b = blockIdx.x;

  float xr0[kF], xr1[kF], xr2[kF];
  float br0[kO], br1[kO], br2[kO];
  const bool has3 = (w < 4) && (l < 32);  // third row: 128 threads, SIMD-balanced

  const int u0r = t >> 5;          // rows 0..511    -> u 0..15
  const int s0r = t & 31;
  const int rot0 = (s0r + u0r) & 31;
  const int u1r = 16 + (t >> 5);   // rows 512..1023 -> u 16..31
  const int rot1 = (s0r + u1r) & 31;
  const int u2r = 32 + w;          // rows 1024..1151 -> u 32..35
  const int rot2 = (l + u2r) & 31;

  // v_pre role constants (threads with l<60): i = w*60+l -> (o,e,uc), u0=uc*12
  const bool vp_act = (l < 60);
  int vp_o = 0, vp_e = 0, vp_u0 = 0;
  if (vp_act) {
    const int i = w * 60 + l;
    vp_o = i / 48;
    const int r = i - vp_o * 48;
    vp_e = r / 3;
    vp_u0 = (r - vp_e * 3) * 12;
  }

  // ---- iteration-invariant W rows for v_pre: 24 float4s in registers ----
#define DECLW(I) float4 wA##I, wB##I;
  DECLW(0) DECLW(1) DECLW(2) DECLW(3) DECLW(4) DECLW(5)
  DECLW(6) DECLW(7) DECLW(8) DECLW(9) DECLW(10) DECLW(11)
#undef DECLW
  if (vp_act) {
    const float* wrow = Wg + ((size_t)(vp_o * kU + vp_u0) * kE + vp_e) * kF;
#define LOADW(I)                                                              \
  {                                                                           \
    const float4* p_ = reinterpret_cast<const float4*>(wrow + (I) * kE * kF); \
    wA##I = p_[0];                                                            \
    wB##I = p_[1];                                                            \
  }
    LOADW(0) LOADW(1) LOADW(2) LOADW(3) LOADW(4) LOADW(5)
    LOADW(6) LOADW(7) LOADW(8) LOADW(9) LOADW(10) LOADW(11)
#undef LOADW
  }

  // ---- prologue: load rows -> regs + swizzled LDS; half-wave butterfly sx ----
#define STAGEROW(XR, N, U, S)                                                 \
  {                                                                           \
    const float4* src_ =                                                      \
        reinterpret_cast<const float4*>(xg + ((size_t)b * kN + (N)) * kF);    \
    const float4 a0_ = src_[0];                                               \
    const float4 a1_ = src_[1];                                               \
    XR[0] = a0_.x; XR[1] = a0_.y; XR[2] = a0_.z; XR[3] = a0_.w;               \
    XR[4] = a1_.x; XR[5] = a1_.y; XR[6] = a1_.z; XR[7] = a1_.w;               \
    const int sl0_ = (((S) << 1) + (U)) & 63;                                 \
    const int sl1_ = (((S) << 1) + 1 + (U)) & 63;                             \
    *reinterpret_cast<float4*>(&s_x[(U) * 256 + sl0_ * 4]) = a0_;             \
    *reinterpret_cast<float4*>(&s_x[(U) * 256 + sl1_ * 4]) = a1_;             \
    float4 r0_ = a0_, r1_ = a1_;                                              \
    _Pragma("unroll")                                                         \
    for (int m_ = 1; m_ <= 16; m_ <<= 1) {                                    \
      r0_.x += __shfl_xor(r0_.x, m_); r0_.y += __shfl_xor(r0_.y, m_);         \
      r0_.z += __shfl_xor(r0_.z, m_); r0_.w += __shfl_xor(r0_.w, m_);         \
      r1_.x += __shfl_xor(r1_.x, m_); r1_.y += __shfl_xor(r1_.y, m_);         \
      r1_.z += __shfl_xor(r1_.z, m_); r1_.w += __shfl_xor(r1_.w, m_);         \
    }                                                                         \
    if ((S) == 0) {                                                           \
      *reinterpret_cast<float4*>(&s_sx[(U) * kF + 0]) = r0_;                  \
      *reinterpret_cast<float4*>(&s_sx[(U) * kF + 4]) = r1_;                  \
    }                                                                         \
  }

  STAGEROW(xr0, t, u0r, s0r)
  STAGEROW(xr1, t + 512, u1r, s0r)
  if (has3) STAGEROW(xr2, 1024 + w * 32 + l, u2r, l)
#undef STAGEROW
#pragma unroll
  for (int o = 0; o < kO; ++o) { br0[o] = 0.f; br1[o] = 0.f; br2[o] = 0.f; }
  __syncthreads();

  for (int it = 0; it <= kIters; ++it) {
    // ---- cx[o][u][f] = sum_s c[o][n]*x[n][f] ----
    // thread (op,u,h): o-pair op, s-half h; 360 active spread as l<46 per wave.
    // Pairing: i = w*46+l, 46 even -> lane parity == i parity, so (h0,h1) of
    // each (op,u) are adjacent lanes; combined via __shfl_xor(1).
    if (it > 0) {
      if (l < 46) {
        const int i = w * 46 + l;
        if (i < 360) {
          const int op  = i / 72;
          const int rem = i - op * 72;
          const int u   = rem >> 1;
          const int h   = rem & 1;
          const int o0  = op * 2, o1 = o0 + 1;
          float4 p00 = make_float4(0.f, 0.f, 0.f, 0.f);
          float4 p01 = make_float4(0.f, 0.f, 0.f, 0.f);
          float4 p10 = make_float4(0.f, 0.f, 0.f, 0.f);
          float4 p11 = make_float4(0.f, 0.f, 0.f, 0.f);
#pragma unroll 4
          for (int j = 0; j < 16; ++j) {
            const int s   = h * 16 + j;
            const int rot = (s + u) & 31;
            const int sl0 = ((s << 1) + u) & 63;
            const int sl1 = ((s << 1) + 1 + u) & 63;
            const float4 xa =
                *reinterpret_cast<const float4*>(&s_x[u * 256 + sl0 * 4]);
            const float4 xb =
                *reinterpret_cast<const float4*>(&s_x[u * 256 + sl1 * 4]);
            const float c0 = s_c[o0 * kN + u * 32 + rot];
            const float c1 = s_c[o1 * kN + u * 32 + rot];
            p00.x += c0 * xa.x; p00.y += c0 * xa.y; p00.z += c0 * xa.z; p00.w += c0 * xa.w;
            p01.x += c0 * xb.x; p01.y += c0 * xb.y; p01.z += c0 * xb.z; p01.w += c0 * xb.w;
            p10.x += c1 * xa.x; p10.y += c1 * xa.y; p10.z += c1 * xa.z; p10.w += c1 * xa.w;
            p11.x += c1 * xb.x; p11.y += c1 * xb.y; p11.z += c1 * xb.z; p11.w += c1 * xb.w;
          }
          // combine the two s-halves (adjacent lanes, same (op,u))
          p00.x += __shfl_xor(p00.x, 1); p00.y += __shfl_xor(p00.y, 1);
          p00.z += __shfl_xor(p00.z, 1); p00.w += __shfl_xor(p00.w, 1);
          p01.x += __shfl_xor(p01.x, 1); p01.y += __shfl_xor(p01.y, 1);
          p01.z += __shfl_xor(p01.z, 1); p01.w += __shfl_xor(p01.w, 1);
          p10.x += __shfl_xor(p10.x, 1); p10.y += __shfl_xor(p10.y, 1);
          p10.z += __shfl_xor(p10.z, 1); p10.w += __shfl_xor(p10.w, 1);
          p11.x += __shfl_xor(p11.x, 1); p11.y += __shfl_xor(p11.y, 1);
          p11.z += __shfl_xor(p11.z, 1); p11.w += __shfl_xor(p11.w, 1);
          if (h == 0) {
            float4* d = reinterpret_cast<float4*>(&s_cx[(o0 * kU + u) * kPitch]);
            d[0] = p00; d[1] = p01;
          } else {
            float4* d = reinterpret_cast<float4*>(&s_cx[(o1 * kU + u) * kPitch]);
            d[0] = p10; d[1] = p11;
          }
        }
      }
      __syncthreads();
    }

    // ---- v_pre partials: thread=(o,e,uc), 480 active; W from REGISTERS ----
    if (vp_act) {
      float accA = 0.f, accB = 0.f;
      if (it == 0) {
#define VPSTEP0(I)                                                            \
  {                                                                           \
    const float4* cp_ =                                                       \
        reinterpret_cast<const float4*>(&s_sx[(vp_u0 + (I)) * kF]);           \
    const float4 c0_ = cp_[0];                                                \
    const float4 c1_ = cp_[1];                                                \
    accA += wA##I.x * c0_.x + wA##I.y * c0_.y + wA##I.z * c0_.z + wA##I.w * c0_.w; \
    accB += wB##I.x * c1_.x + wB##I.y * c1_.y + wB##I.z * c1_.z + wB##I.w * c1_.w; \
  }
        VPSTEP0(0) VPSTEP0(1) VPSTEP0(2) VPSTEP0(3) VPSTEP0(4) VPSTEP0(5)
        VPSTEP0(6) VPSTEP0(7) VPSTEP0(8) VPSTEP0(9) VPSTEP0(10) VPSTEP0(11)
#undef VPSTEP0
        accA = (accA + accB) * 0.1f;
      } else {
#define VPSTEP(I)                                                             \
  {                                                                           \
    const float4* cp_ = reinterpret_cast<const float4*>(                      \
        &s_cx[(vp_o * kU + vp_u0 + (I)) * kPitch]);                           \
    const float4 c0_ = cp_[0];                                                \
    const float4 c1_ = cp_[1];                                                \
    accA += wA##I.x * c0_.x + wA##I.y * c0_.y + wA##I.z * c0_.z + wA##I.w * c0_.w; \
    accB += wB##I.x * c1_.x + wB##I.y * c1_.y + wB##I.z * c1_.z + wB##I.w * c1_.w; \
  }
        VPSTEP(0) VPSTEP(1) VPSTEP(2) VPSTEP(3) VPSTEP(4) VPSTEP(5)
        VPSTEP(6) VPSTEP(7) VPSTEP(8) VPSTEP(9) VPSTEP(10) VPSTEP(11)
#undef VPSTEP
        accA += accB;
      }
      s_vp[(vp_o * kE + vp_e) * 3 + ((w * 60 + l) - vp_o * 48 - vp_e * 3)] = accA;
    }
    __syncthreads();

    // ---- final pass: squash + store output, done ----
    if (it == kIters) {
      if (t < kO * kE) {
        const float vsum = s_vp[t * 3 + 0] + s_vp[t * 3 + 1] + s_vp[t * 3 + 2];
        float n2 = vsum * vsum;
#pragma unroll
        for (int m = 1; m <= 8; m <<= 1) n2 += __shfl_xor(n2, m);
        const float scale = sqrtf(n2) / (1.f + n2);
        outg[(size_t)b * kO * kE + t] = vsum * scale;
      }
      break;
    }

    // ---- wv[o][u][f] = sum_e W[o][u][e][f]*v[o][e]; 360 active as l<45 ----
    // squash folded in; v rebuilt into named float4s (broadcast s_vp reads)
    if (l < 45) {
      const int i = w * 45 + l;  // 0..359
      const int o = i / 36;
      const int u = i - o * 36;
#define SUMVP(E_) (s_vp[(o * kE + (E_)) * 3 + 0] + \
                   s_vp[(o * kE + (E_)) * 3 + 1] + \
                   s_vp[(o * kE + (E_)) * 3 + 2])
      float4 va, vb, vc, vd;
      va.x = SUMVP(0);  va.y = SUMVP(1);  va.z = SUMVP(2);  va.w = SUMVP(3);
      vb.x = SUMVP(4);  vb.y = SUMVP(5);  vb.z = SUMVP(6);  vb.w = SUMVP(7);
      vc.x = SUMVP(8);  vc.y = SUMVP(9);  vc.z = SUMVP(10); vc.w = SUMVP(11);
      vd.x = SUMVP(12); vd.y = SUMVP(13); vd.z = SUMVP(14); vd.w = SUMVP(15);
#undef SUMVP
      const float n2 =
          va.x * va.x + va.y * va.y + va.z * va.z + va.w * va.w +
          vb.x * vb.x + vb.y * vb.y + vb.z * vb.z + vb.w * vb.w +
          vc.x * vc.x + vc.y * vc.y + vc.z * vc.z + vc.w * vc.w +
          vd.x * vd.x + vd.y * vd.y + vd.z * vd.z + vd.w * vd.w;
      const float scale = sqrtf(n2) / (1.f + n2);
      const float* wbase = Wg + (size_t)(o * kU + u) * kE * kF;
      float4 acc0 = make_float4(0.f, 0.f, 0.f, 0.f);
      float4 acc1 = make_float4(0.f, 0.f, 0.f, 0.f);
#define WSTEP(VE_, E_)                                                        \
  {                                                                           \
    const float4* wp = reinterpret_cast<const float4*>(wbase + (E_) * kF);    \
    const float4 w0 = wp[0];                                                  \
    const float4 w1 = wp[1];                                                  \
    const float ve = (VE_) * scale;                                           \
    acc0.x += ve * w0.x; acc0.y += ve * w0.y;                                 \
    acc0.z += ve * w0.z; acc0.w += ve * w0.w;                                 \
    acc1.x += ve * w1.x; acc1.y += ve * w1.y;                                 \
    acc1.z += ve * w1.z; acc1.w += ve * w1.w;                                 \
  }
      WSTEP(va.x, 0)  WSTEP(va.y, 1)  WSTEP(va.z, 2)  WSTEP(va.w, 3)
      WSTEP(vb.x, 4)  WSTEP(vb.y, 5)  WSTEP(vb.z, 6)  WSTEP(vb.w, 7)
      WSTEP(vc.x, 8)  WSTEP(vc.y, 9)  WSTEP(vc.z, 10) WSTEP(vc.w, 11)
      WSTEP(vd.x, 12) WSTEP(vd.y, 13) WSTEP(vd.z, 14) WSTEP(vd.w, 15)
#undef WSTEP
      float4* d = reinterpret_cast<float4*>(&s_wv[(o * kU + u) * kPitch]);
      d[0] = acc0;
      d[1] = acc1;
    }
    __syncthreads();

    // ---- b[o,n] += x[n,:].wv[o,u,:]; thread-local softmax over o; write c ----
#define BSMROW(XR, BR, U, ROT)                                                \
  {                                                                           \
    float mx_ = -3.4e38f;                                                     \
    _Pragma("unroll")                                                         \
    for (int o_ = 0; o_ < kO; ++o_) {                                         \
      const float4* wp_ =                                                     \
          reinterpret_cast<const float4*>(&s_wv[(o_ * kU + (U)) * kPitch]);   \
      const float4 w0_ = wp_[0];                                              \
      const float4 w1_ = wp_[1];                                              \
      BR[o_] += w0_.x * XR[0] + w0_.y * XR[1] + w0_.z * XR[2] + w0_.w * XR[3] \
              + w1_.x * XR[4] + w1_.y * XR[5] + w1_.z * XR[6] + w1_.w * XR[7];\
      mx_ = fmaxf(mx_, BR[o_]);                                               \
    }                                                                         \
    float ex_[kO];                                                            \
    float sum_ = 0.f;                                                         \
    _Pragma("unroll")                                                         \
    for (int o_ = 0; o_ < kO; ++o_) {                                         \
      ex_[o_] = __expf(BR[o_] - mx_);                                         \
      sum_ += ex_[o_];                                                        \
    }                                                                         \
    const float inv_ = 1.f / sum_;                                            \
    _Pragma("unroll")                                                         \
    for (int o_ = 0; o_ < kO; ++o_)                                           \
      s_c[o_ * kN + (U) * 32 + (ROT)] = ex_[o_] * inv_;                       \
  }
    BSMROW(xr0, br0, u0r, rot0)
    BSMROW(xr1, br1, u1r, rot1)
    if (has3) BSMROW(xr2, br2, u2r, rot2)
#undef BSMROW
    __syncthreads();
  }
}

}  // namespace

extern "C" void kernel_launch(void* const* d_in, const int* in_sizes, int n_in,
                              void* d_out, int out_size, void* d_ws, size_t ws_size,
                              hipStream_t stream) {
  const float* x = (const float*)d_in[0];  // (B, 1152, 8) fp32
  const float* W = (const float*)d_in[1];  // (10, 36, 16, 8) fp32
  float* out = (float*)d_out;              // (B, 10, 16) fp32

  const int batch = in_sizes[0] / (kN * kF);  // 256
  caps_routing_kernel<<<dim3(batch), dim3(kThreads), 0, stream>>>(x, W, out);
}